// Round 8
// baseline (185.127 us; speedup 1.0000x reference)
//
#include <hip/hip_runtime.h>
#include <hip/hip_bf16.h>
#include <cstdint>

#define KDIM 512
#define BM 128
#define BN 512      // full N: A read exactly once; energy completed per block
#define BK 32
#define M_MAIN 100352   // 512*196
#define NPIX 196
#define BATCH 512

typedef float f32x4 __attribute__((ext_vector_type(4)));
typedef short s16x8 __attribute__((ext_vector_type(8)));

__device__ __forceinline__ short f2bf(float f) {
    uint32_t u = __float_as_uint(f);
    uint32_t r = u + 0x7FFFu + ((u >> 16) & 1u);   // round-to-nearest-even
    return (short)(r >> 16);
}

__device__ __forceinline__ void gload_lds16(const void* g, void* l) {
    __builtin_amdgcn_global_load_lds(
        (const __attribute__((address_space(1))) void*)g,
        (__attribute__((address_space(3))) void*)l, 16, 0, 0);
}

__device__ __forceinline__ uint32_t pkbf(float lo, float hi) {
    __hip_bfloat162 p = __float22bfloat162_rn(float2{lo, hi});
    return *reinterpret_cast<uint32_t*>(&p);
}

// Transpose + convert W [K][A] fp32 -> Wt [A][K] bf16 for both weight matrices.
__global__ void prep_w(const float* __restrict__ W_enc, const float* __restrict__ W_dec,
                       short* __restrict__ Wt_enc, short* __restrict__ Wt_dec) {
    int a = blockIdx.x;
    int k = threadIdx.x;
    const float* W = blockIdx.y ? W_dec : W_enc;
    short* Wt = blockIdx.y ? Wt_dec : Wt_enc;
    Wt[a * KDIM + k] = f2bf(W[(size_t)k * KDIM + a]);
}

// 128x512 tile (full N), BK=32, 512 thr = 8 waves as 1M x 8N; wave-tile
// 128x64, acc[8][4].  Per-CU per-K-tile byte supply: A 16KB (HBM/LLC path) +
// B 32KB (L2-hit path, universally shared 512KB) -- A-supply-bound by design.
// Simple proven 2-phase loop (one barrier per tile); loads issued a full tile
// ahead (~1.6k cyc) so the barrier drain is cheap.
// BK=32 LDS swizzle (derived from bank-group (4r+s)%8): phys_slot =
// logical_slot ^ ((row>>1)&3) -- conflict-free for ds_write_b128,
// global_load_lds (source pre-swizzled, rule #21) and ds_read_b128.
// Chunk-stride loop over M: grid=768 (3 exact rounds), blocks 0..15 take the
// 16 extra chunks (784 total), eliminating the 4th-round tail.
// EPI==0: out[row][col] = acc + b1[col] + b2[col]   (att_dec' precompute)
// EPI==1: out[row] = full energy = sum_cols relu(acc + attdec[row/196][col]) * wfull[col]
template <int EPI>
__launch_bounds__(512, 1)
__global__ void gemm_fused(const float* __restrict__ A, int M,
                           const short* __restrict__ Bt,
                           const float* __restrict__ b1, const float* __restrict__ b2,
                           const float* __restrict__ attdec, const float* __restrict__ wfull,
                           float* __restrict__ outp) {
    __shared__ short lds_a[2][BM][BK];   // 16 KB
    __shared__ short lds_b[2][BN][BK];   // 64 KB

    const int tid = threadIdx.x;
    const int wave = tid >> 6;
    const int lane = tid & 63;
    const int lcol = lane & 15;
    const int lrg = (lane >> 4) * 4;
    const int swz = ((lane & 15) >> 1) & 3;        // read-side row-swizzle term
    const int nch = M >> 7;                        // chunks of 128 rows

    for (int ch = blockIdx.x; ch < nch; ch += gridDim.x) {
        const int r0 = ch << 7;

        f32x4 areg[2];
        // A tile 128x32 f32: thread owns row tid>>2, f32s (tid&3)*8..+7
        auto loadA = [&](int kt) {
            int row = tid >> 2, c8 = (tid & 3) * 8;
            const float* p = A + (size_t)(r0 + row) * KDIM + kt * BK + c8;
            areg[0] = *(const f32x4*)p;
            areg[1] = *(const f32x4*)(p + 4);
        };
        auto writeA = [&](int buf) {
            int row = tid >> 2;
            int sl = (tid & 3) ^ ((row >> 1) & 3);     // phys slot
            uint4 w;
            w.x = pkbf(areg[0][0], areg[0][1]);
            w.y = pkbf(areg[0][2], areg[0][3]);
            w.z = pkbf(areg[1][0], areg[1][1]);
            w.w = pkbf(areg[1][2], areg[1][3]);
            *reinterpret_cast<uint4*>(&lds_a[buf][row][sl * 8]) = w;
        };
        // B tile 512x32 bf16: per wave 4 issues of 16 rows (64 lanes x 16B).
        auto stageB = [&](int buf, int kt) {
#pragma unroll
            for (int i = 0; i < 4; ++i) {
                int rb = wave * 64 + i * 16;
                // lane l -> phys (row rb+(l>>2), slot l&3); source slot pre-swizzled
                int srcsl = (lane & 3) ^ ((lane >> 3) & 3);
                const short* g = Bt + (size_t)(rb + (lane >> 2)) * KDIM + kt * BK + srcsl * 8;
                gload_lds16(g, &lds_b[buf][rb][0]);
            }
        };

        f32x4 acc[8][4];
#pragma unroll
        for (int i = 0; i < 8; ++i)
#pragma unroll
            for (int j = 0; j < 4; ++j)
                acc[i][j] = (f32x4){0.f, 0.f, 0.f, 0.f};

        auto compute = [&](int buf) {
            s16x8 af[8], bf[4];
#pragma unroll
            for (int fm = 0; fm < 8; ++fm) {
                int ra = fm * 16 + lcol;
                int sl = (lane >> 4) ^ swz;
                af[fm] = *(const s16x8*)&lds_a[buf][ra][sl * 8];
            }
#pragma unroll
            for (int fn = 0; fn < 4; ++fn) {
                int rb = wave * 64 + fn * 16 + lcol;
                int sl = (lane >> 4) ^ swz;
                bf[fn] = *(const s16x8*)&lds_b[buf][rb][sl * 8];
            }
#pragma unroll
            for (int fm = 0; fm < 8; ++fm)
#pragma unroll
                for (int fn = 0; fn < 4; ++fn)
                    acc[fm][fn] = __builtin_amdgcn_mfma_f32_16x16x32_bf16(af[fm], bf[fn], acc[fm][fn], 0, 0, 0);
        };

        // prologue: tile 0
        loadA(0);
        stageB(0, 0);
        writeA(0);
        __syncthreads();

        const int nk = KDIM / BK;   // 16
        for (int t = 0; t < nk; ++t) {
            int cur = t & 1;
            if (t + 1 < nk) {
                loadA(t + 1);
                stageB(cur ^ 1, t + 1);
            }
            compute(cur);
            if (t + 1 < nk) writeA(cur ^ 1);
            __syncthreads();
        }

        if constexpr (EPI == 0) {
#pragma unroll
            for (int fm = 0; fm < 8; ++fm)
#pragma unroll
                for (int fn = 0; fn < 4; ++fn) {
                    int col = wave * 64 + fn * 16 + lcol;
                    float bias = b1[col] + b2[col];
#pragma unroll
                    for (int reg = 0; reg < 4; ++reg) {
                        int row = r0 + fm * 16 + lrg + reg;
                        outp[(size_t)row * KDIM + col] = acc[fm][fn][reg] + bias;
                    }
                }
        } else {
            // chunk spans <=2 batches (128 < 196): preload both attdec rows
            const int b0 = r0 / NPIX;
            const int b1i = min(b0 + 1, BATCH - 1);
            float wfv[4], ad0[4], ad1[4];
#pragma unroll
            for (int fn = 0; fn < 4; ++fn) {
                int col = wave * 64 + fn * 16 + lcol;
                wfv[fn] = wfull[col];
                ad0[fn] = attdec[(size_t)b0 * KDIM + col];
                ad1[fn] = attdec[(size_t)b1i * KDIM + col];
            }
            float* ebuf = reinterpret_cast<float*>(lds_a);   // [8 waves][128 rows] = 4KB
#pragma unroll
            for (int fm = 0; fm < 8; ++fm) {
#pragma unroll
                for (int reg = 0; reg < 4; ++reg) {
                    int rl = fm * 16 + lrg + reg;
                    bool hi = ((r0 + rl) / NPIX) != b0;
                    float es = 0.f;
#pragma unroll
                    for (int fn = 0; fn < 4; ++fn) {
                        float ad = hi ? ad1[fn] : ad0[fn];
                        float v = acc[fm][fn][reg] + ad;
                        v = fmaxf(v, 0.f);
                        es = fmaf(v, wfv[fn], es);
                    }
#pragma unroll
                    for (int m = 1; m < 16; m <<= 1) es += __shfl_xor(es, m);
                    if (lcol == 0) ebuf[wave * BM + rl] = es;
                }
            }
            __syncthreads();
            if (tid < BM) {
                float s = 0.f;
#pragma unroll
                for (int w = 0; w < 8; ++w) s += ebuf[w * BM + tid];
                outp[r0 + tid] = s;
            }
        }
        __syncthreads();   // protect lds_a/ebuf before next chunk's prologue
    }
}

// One block per batch element: softmax over 196 energies, write alpha,
// then context[b][e] = sum_p enc[b][p][e] * alpha[p].
__global__ void softmax_ctx(const float* __restrict__ enc, const float* __restrict__ energy,
                            float* __restrict__ out) {
    const int b = blockIdx.x;
    const int t = threadIdx.x;  // 256
    __shared__ float sal[NPIX];
    __shared__ float wred[4];

    float e = (t < NPIX) ? energy[b * NPIX + t] : -1e30f;
    float m = e;
#pragma unroll
    for (int d = 1; d < 64; d <<= 1) m = fmaxf(m, __shfl_xor(m, d));
    if ((t & 63) == 0) wred[t >> 6] = m;
    __syncthreads();
    m = fmaxf(fmaxf(wred[0], wred[1]), fmaxf(wred[2], wred[3]));

    float ex = (t < NPIX) ? __expf(e - m) : 0.f;
    float sm = ex;
#pragma unroll
    for (int d = 1; d < 64; d <<= 1) sm += __shfl_xor(sm, d);
    __syncthreads();
    if ((t & 63) == 0) wred[t >> 6] = sm;
    __syncthreads();
    sm = wred[0] + wred[1] + wred[2] + wred[3];

    float al = ex / sm;
    if (t < NPIX) {
        sal[t] = al;
        out[BATCH * KDIM + b * NPIX + t] = al;
    }
    __syncthreads();

    // context: each thread owns cols 2t, 2t+1
    float c0 = 0.f, c1 = 0.f;
    const float* eb = enc + (size_t)b * NPIX * KDIM;
    const int col = 2 * t;
#pragma unroll 4
    for (int p = 0; p < NPIX; ++p) {
        float a = sal[p];
        float2 v = *(const float2*)(eb + (size_t)p * KDIM + col);
        c0 = fmaf(v.x, a, c0);
        c1 = fmaf(v.y, a, c1);
    }
    out[b * KDIM + col] = c0;
    out[b * KDIM + col + 1] = c1;
}

extern "C" void kernel_launch(void* const* d_in, const int* in_sizes, int n_in,
                              void* d_out, int out_size, void* d_ws, size_t ws_size,
                              hipStream_t stream) {
    const float* encoder = (const float*)d_in[0];   // [512,196,512]
    const float* dec_h   = (const float*)d_in[1];   // [512,512]
    const float* W_enc   = (const float*)d_in[2];   // [512,512]
    const float* b_enc   = (const float*)d_in[3];   // [512]
    const float* W_dec   = (const float*)d_in[4];   // [512,512]
    const float* b_decv  = (const float*)d_in[5];   // [512]
    const float* w_full  = (const float*)d_in[6];   // [512]
    float* out = (float*)d_out;                     // context [512,512] ++ alpha [512,196]

    short* wt_enc = (short*)d_ws;                   // 512*512 bf16
    short* wt_dec = wt_enc + 512 * 512;             // 512*512 bf16
    float* attdec = (float*)(wt_dec + 512 * 512);   // [512][512] fp32 (incl. both biases)
    float* energy = attdec + 512 * 512;             // [100352] fp32 (complete rows)

    // 1) weight transpose + bf16 convert
    prep_w<<<dim3(512, 2), 512, 0, stream>>>(W_enc, W_dec, wt_enc, wt_dec);

    // 2) att_dec' = dec_h @ W_dec + b_dec + b_enc   (store fp32 [512][512])
    gemm_fused<0><<<dim3(4), 512, 0, stream>>>(dec_h, 512, wt_dec,
                                               b_enc, b_decv, nullptr, nullptr, attdec);

    // 3) main fused GEMM -> full energies (784 chunks over 768 blocks = 3 exact rounds)
    gemm_fused<1><<<dim3(768), 512, 0, stream>>>(encoder, M_MAIN, wt_enc,
                                                 nullptr, nullptr, attdec, w_full, energy);

    // 4) softmax + context
    softmax_ctx<<<dim3(BATCH), 256, 0, stream>>>(encoder, energy, out);
}